// Round 4
// baseline (50.296 us; speedup 1.0000x reference)
//
#include <hip/hip_runtime.h>
#include <math.h>

#define MAXP 145          // real pos tokens max (n = 145)
#define VROWS 148         // vpos rows (padded, rows >= MAXP zeroed)
#define PJ   152          // LDS row stride for w_s / att2 / betaT
#define EPSF 1e-5f
#define NPAR 130048

// ---- workspace layout (floats) ----
#define WS_VPOS 0                      // [VROWS][64]
#define WS_VCLS (VROWS*64)             // [64]
#define WS_UV   (WS_VCLS+64)           // [64]
#define WS_BETA (WS_UV+64)             // betaT [4][PJ]
#define WS_ALGA (WS_BETA+4*PJ)         // alpha[4], gamma[4]

// wave-local "barrier": all LDS deps in k_main are intra-wave (every array is
// indexed [wave] on both sides), so a full s_barrier is pure overhead. This
// drains LDS ops and stops the compiler from caching LDS values across it.
#define WAVE_SYNC() asm volatile("s_waitcnt lgkmcnt(0)" ::: "memory")

// K1: blocks 0..144 -> vpos row j, betaT[.][j]; block 145 -> vcls, uv, alpha, gamma, zero rows
__global__ __launch_bounds__(64) void k_pre(const float* __restrict__ pe,
                                            const float* __restrict__ ct,
                                            const float* __restrict__ W,   // in_proj_w (192,64)
                                            const float* __restrict__ bq,  // in_proj_b (192)
                                            float* __restrict__ ws)
{
    const int j = blockIdx.x;
    const int o = threadIdx.x;   // 0..63
    const float4* wq4 = (const float4*)(W + o*64);
    const float4* wk4 = (const float4*)(W + (64 + o)*64);
    const float4* wv4 = (const float4*)(W + (128 + o)*64);
    const float4* ct4 = (const float4*)ct;

    if (j < MAXP) {
        const float4* p4 = (const float4*)(pe + j*64);
        float sk = bq[64 + o], sv = bq[128 + o], sq = bq[o];
        #pragma unroll
        for (int e = 0; e < 16; ++e) {
            float4 k4 = wk4[e], v4 = wv4[e], q4 = wq4[e], pp = p4[e], cc = ct4[e];
            sk += k4.x*pp.x + k4.y*pp.y + k4.z*pp.z + k4.w*pp.w;
            sv += v4.x*pp.x + v4.y*pp.y + v4.z*pp.z + v4.w*pp.w;
            sq += q4.x*cc.x + q4.y*cc.y + q4.z*cc.z + q4.w*cc.w;
        }
        ws[WS_VPOS + j*64 + o] = sv;                      // coalesced row write
        float r = sq * sk;
        #pragma unroll
        for (int off = 1; off < 16; off <<= 1) r += __shfl_xor(r, off);
        if ((o & 15) == 0) ws[WS_BETA + (o >> 4)*PJ + j] = r;
    } else {
        float sq = bq[o], sk = bq[64 + o], sv = bq[128 + o], suk = 0.f, suv = 0.f;
        #pragma unroll
        for (int e = 0; e < 16; ++e) {
            float4 k4 = wk4[e], v4 = wv4[e], q4 = wq4[e], cc = ct4[e];
            sq += q4.x*cc.x + q4.y*cc.y + q4.z*cc.z + q4.w*cc.w;
            sk += k4.x*cc.x + k4.y*cc.y + k4.z*cc.z + k4.w*cc.w;
            sv += v4.x*cc.x + v4.y*cc.y + v4.z*cc.z + v4.w*cc.w;
            suk += k4.x + k4.y + k4.z + k4.w;
            suv += v4.x + v4.y + v4.z + v4.w;
        }
        ws[WS_VCLS + o] = sv;
        ws[WS_UV + o]   = suv;
        for (int r = MAXP; r < VROWS; ++r) ws[WS_VPOS + r*64 + o] = 0.f;
        float a = sq * suk, g = sq * sk;
        #pragma unroll
        for (int off = 1; off < 16; off <<= 1) {
            a += __shfl_xor(a, off);
            g += __shfl_xor(g, off);
        }
        if ((o & 15) == 0) { ws[WS_ALGA + (o >> 4)] = a; ws[WS_ALGA + 4 + (o >> 4)] = g; }
    }
}

template<int L>
__device__ __forceinline__ void seq_compute(
    const float* __restrict__ xb,   // x + b*NPAR
    int start, int kno, int outidx, int k, int lane,
    const float* __restrict__ ct,
    const float* __restrict__ Wo,  const float* __restrict__ bo,
    const float* __restrict__ L1w, const float* __restrict__ b1,
    const float* __restrict__ L2w, const float* __restrict__ b2,
    const float* __restrict__ ln1w, const float* __restrict__ ln1b,
    const float* __restrict__ ln2w, const float* __restrict__ ln2b,
    const float* __restrict__ ws,
    float* __restrict__ out,
    float* __restrict__ w_s,    // [PJ]      this wave's slice
    float* __restrict__ att2,   // [4][PJ]
    float* __restrict__ sc4,    // [8]
    float* __restrict__ o_s,    // [64]
    float* __restrict__ h1_s,   // [64]
    float* __restrict__ r_s)    // [96]
{
    constexpr int N  = L + 1;            // tokens (incl. bias token)
    constexpr int S  = N + 1;            // + cls
    constexpr int NS = (S + 15) / 16;    // score slots per lane
    constexpr int N4 = (N + 3) / 4;      // float4 chunks

    const float* vpos  = ws + WS_VPOS;
    const float* vcls  = ws + WS_VCLS;
    const float* uv    = ws + WS_UV;
    const float* betaT = ws + WS_BETA;
    const float* alga  = ws + WS_ALGA;

    // ---- load scalar params ----
    if (lane * 4 < L) {
        float4 v = *(const float4*)(xb + start + (size_t)k * L + lane*4);
        *(float4*)(w_s + lane*4) = v;
    }
    if (lane == 0) w_s[L] = xb[start + (size_t)kno * L + k];
    WAVE_SYNC();

    // ---- head-parallel scores + softmax in registers ----
    const int e = lane & 15;
    const int h = lane >> 4;
    const float alpha = alga[h];
    const float gam   = alga[4 + h];
    const float* bh   = betaT + h*PJ;

    float p[NS];
    float m = -1e30f;
    #pragma unroll
    for (int t = 0; t < NS; ++t) {
        const int s = e + 16*t;
        float v = -1e30f;
        if (s < S) v = (s == 0) ? gam : fmaf(alpha, w_s[s-1], bh[s-1]);
        v *= 0.25f;
        p[t] = v;
        m = fmaxf(m, v);
    }
    #pragma unroll
    for (int off = 1; off < 16; off <<= 1) m = fmaxf(m, __shfl_xor(m, off));

    float sum = 0.f;
    #pragma unroll
    for (int t = 0; t < NS; ++t) {
        const int s = e + 16*t;
        if (s < S) { float ex = __expf(p[t] - m); p[t] = ex; sum += ex; }
    }
    #pragma unroll
    for (int off = 1; off < 16; off <<= 1) sum += __shfl_xor(sum, off);
    const float inv = 1.f / sum;

    float wsl = 0.f;
    #pragma unroll
    for (int t = 0; t < NS; ++t) {
        const int s = e + 16*t;
        if (s < S) {
            float a = p[t] * inv;
            if (s == 0) sc4[h] = a;
            else {
                att2[h*PJ + (s-1)] = a;
                wsl += a * w_s[s-1];
            }
        }
    }
    #pragma unroll
    for (int off = 1; off < 16; off <<= 1) wsl += __shfl_xor(wsl, off);
    if (e == 0) sc4[4 + h] = wsl;
    { int jj = N + e; if (jj < 4*N4) att2[h*PJ + jj] = 0.f; }
    WAVE_SYNC();

    // ---- o[d] = wsum*uv + a0*vcls + sum_j a[j]*vpos[j][d]  (fully unrolled) ----
    const int d  = lane;
    const int hd = d >> 4;
    {
        const float a0   = sc4[hd];
        const float wsum = sc4[4 + hd];
        const float4* arow = (const float4*)(att2 + hd*PJ);
        float a0c = 0.f, a1c = 0.f, a2c = 0.f, a3c = 0.f;
        #pragma unroll
        for (int t = 0; t < N4; ++t) {
            float4 a = arow[t];
            const float* vp = vpos + t*256 + d;
            a0c += a.x * vp[0];
            a1c += a.y * vp[64];
            a2c += a.z * vp[128];
            a3c += a.w * vp[192];
        }
        o_s[d] = (a0c + a1c) + (a2c + a3c) + wsum*uv[d] + a0*vcls[d];
    }
    WAVE_SYNC();

    // ---- out proj + residual(cls) + LN1 ----
    float op = bo[d];
    {
        const float4* wr = (const float4*)(Wo + d*64);
        const float4* os = (const float4*)o_s;
        float ax=0, ay=0, az=0, aw=0;
        #pragma unroll
        for (int t = 0; t < 16; ++t) {
            float4 w4 = wr[t], o4 = os[t];
            ax += w4.x*o4.x; ay += w4.y*o4.y; az += w4.z*o4.z; aw += w4.w*o4.w;
        }
        op += (ax + ay) + (az + aw);
    }
    float pre = ct[d] + op;
    float mu = pre;
    #pragma unroll
    for (int off = 32; off; off >>= 1) mu += __shfl_xor(mu, off);
    mu *= (1.f/64.f);
    float dv = pre - mu;
    float var = dv*dv;
    #pragma unroll
    for (int off = 32; off; off >>= 1) var += __shfl_xor(var, off);
    var *= (1.f/64.f);
    float h1 = dv * rsqrtf(var + EPSF) * ln1w[d] + ln1b[d];
    h1_s[d] = h1;
    WAVE_SYNC();

    // ---- FF1 (96 outputs) + relu ----
    {
        const float4* hv = (const float4*)h1_s;
        {
            const float4* r1 = (const float4*)(L1w + lane*64);
            float ax=0, ay=0, az=0, aw=0;
            #pragma unroll
            for (int t = 0; t < 16; ++t) {
                float4 w4 = r1[t], h4 = hv[t];
                ax += w4.x*h4.x; ay += w4.y*h4.y; az += w4.z*h4.z; aw += w4.w*h4.w;
            }
            r_s[lane] = fmaxf(b1[lane] + (ax+ay) + (az+aw), 0.f);
        }
        if (lane < 32) {
            const float4* r1 = (const float4*)(L1w + (64 + lane)*64);
            float ax=0, ay=0, az=0, aw=0;
            #pragma unroll
            for (int t = 0; t < 16; ++t) {
                float4 w4 = r1[t], h4 = hv[t];
                ax += w4.x*h4.x; ay += w4.y*h4.y; az += w4.z*h4.z; aw += w4.w*h4.w;
            }
            r_s[64 + lane] = fmaxf(b1[64 + lane] + (ax+ay) + (az+aw), 0.f);
        }
    }
    WAVE_SYNC();

    // ---- FF2 + residual + LN2 ----
    float f2 = b2[d];
    {
        const float4* r2 = (const float4*)(L2w + d*96);
        const float4* rv = (const float4*)r_s;
        float ax=0, ay=0, az=0, aw=0;
        #pragma unroll
        for (int t = 0; t < 24; ++t) {
            float4 w4 = r2[t], h4 = rv[t];
            ax += w4.x*h4.x; ay += w4.y*h4.y; az += w4.z*h4.z; aw += w4.w*h4.w;
        }
        f2 += (ax + ay) + (az + aw);
    }
    float pre2 = h1 + f2;
    float mu2 = pre2;
    #pragma unroll
    for (int off = 32; off; off >>= 1) mu2 += __shfl_xor(mu2, off);
    mu2 *= (1.f/64.f);
    float dv2 = pre2 - mu2;
    float var2 = dv2*dv2;
    #pragma unroll
    for (int off = 32; off; off >>= 1) var2 += __shfl_xor(var2, off);
    var2 *= (1.f/64.f);
    float y = dv2 * rsqrtf(var2 + EPSF) * ln2w[d] + ln2b[d];

    float* po = out + (size_t)outidx * 128;
    po[d]      = y;
    po[64 + d] = y;   // tile (1,1,2)
}

// K2: 256 threads = 4 independent waves, each wave = one sequence. 1024 blocks.
__global__ __launch_bounds__(256, 4) void k_main(
    const float* __restrict__ x,
    const float* __restrict__ ct,
    const float* __restrict__ Wo,  const float* __restrict__ bo,
    const float* __restrict__ L1w, const float* __restrict__ b1,
    const float* __restrict__ L2w, const float* __restrict__ b2,
    const float* __restrict__ ln1w, const float* __restrict__ ln1b,
    const float* __restrict__ ln2w, const float* __restrict__ ln2b,
    const float* __restrict__ ws,
    float* __restrict__ out)
{
    __shared__ float w_s [4][PJ];
    __shared__ float att2[4][4][PJ];
    __shared__ float sc4 [4][8];
    __shared__ float o_s [4][64];
    __shared__ float h1_s[4][64];
    __shared__ float r_s [4][96];

    const int wave = threadIdx.x >> 6;
    const int lane = threadIdx.x & 63;
    const int bid  = blockIdx.x;

    if (bid < 256) {
        int g = bid*4 + wave; int b = g >> 8, k = g & 255;
        seq_compute<72>(x + (size_t)b*NPAR, 0, 256, b*1024 + k, k, lane,
                        ct, Wo, bo, L1w, b1, L2w, b2, ln1w, ln1b, ln2w, ln2b, ws, out,
                        w_s[wave], &att2[wave][0][0], sc4[wave], o_s[wave], h1_s[wave], r_s[wave]);
    } else if (bid < 512) {
        int g = (bid-256)*4 + wave; int b = g >> 8, k = g & 255;
        seq_compute<144>(x + (size_t)b*NPAR, 18688, 256, b*1024 + 256 + k, k, lane,
                        ct, Wo, bo, L1w, b1, L2w, b2, ln1w, ln1b, ln2w, ln2b, ws, out,
                        w_s[wave], &att2[wave][0][0], sc4[wave], o_s[wave], h1_s[wave], r_s[wave]);
    } else {
        int g = (bid-512)*4 + wave; int b = g >> 9, k = g & 511;
        seq_compute<144>(x + (size_t)b*NPAR, 55808, 512, b*1024 + 512 + k, k, lane,
                        ct, Wo, bo, L1w, b1, L2w, b2, ln1w, ln1b, ln2w, ln2b, ws, out,
                        w_s[wave], &att2[wave][0][0], sc4[wave], o_s[wave], h1_s[wave], r_s[wave]);
    }
}

extern "C" void kernel_launch(void* const* d_in, const int* in_sizes, int n_in,
                              void* d_out, int out_size, void* d_ws, size_t ws_size,
                              hipStream_t stream) {
    const float* x    = (const float*)d_in[0];
    const float* pe   = (const float*)d_in[1];
    const float* ct   = (const float*)d_in[2];
    const float* Wq   = (const float*)d_in[3];
    const float* bq   = (const float*)d_in[4];
    const float* Wo   = (const float*)d_in[5];
    const float* bo   = (const float*)d_in[6];
    const float* L1w  = (const float*)d_in[7];
    const float* b1   = (const float*)d_in[8];
    const float* L2w  = (const float*)d_in[9];
    const float* b2   = (const float*)d_in[10];
    const float* ln1w = (const float*)d_in[11];
    const float* ln1b = (const float*)d_in[12];
    const float* ln2w = (const float*)d_in[13];
    const float* ln2b = (const float*)d_in[14];
    float* out = (float*)d_out;
    float* ws  = (float*)d_ws;

    k_pre <<<MAXP + 1, 64, 0, stream>>>(pe, ct, Wq, bq, ws);
    k_main<<<1024, 256, 0, stream>>>(x, ct, Wo, bo, L1w, b1, L2w, b2,
                                     ln1w, ln1b, ln2w, ln2b, ws, out);
}

// Round 5
// 23.149 us; speedup vs baseline: 2.1727x; 2.1727x over previous
//
#include <hip/hip_runtime.h>
#include <math.h>

#define NPAR 130048
#define EPSF 1e-5f

// ---- strides chosen so stride%8==4 -> conflict-free ds_read_b128 across 64 lanes ----
#define VSTR  148            // vposT / betaT / w_s row stride (floats)
#define WSTR  68             // Wo / L1w row stride
#define L2STR 100            // L2w row stride

// ---- LDS layout (float offsets) ----
#define OFF_VPOST 0                          // [64][VSTR]
#define OFF_WO    (64*VSTR)                  // 9472  [64][WSTR]
#define OFF_L1    (OFF_WO + 64*WSTR)         // 13824 [96][WSTR]
#define OFF_L2    (OFF_L1 + 96*WSTR)         // 20352 [64][L2STR]
#define OFF_BETA  (OFF_L2 + 64*L2STR)        // 26752 [4][VSTR]
#define OFF_SM    (OFF_BETA + 4*VSTR)        // 27344
#define SM_CT   0
#define SM_BO   64
#define SM_B1   128
#define SM_B2   224
#define SM_LN1W 288
#define SM_LN1B 352
#define SM_LN2W 416
#define SM_LN2B 480
#define SM_VCLS 544
#define SM_UV   608
#define SM_ALGA 672
#define SM_SIZE 680
#define SHARED_FLOATS (OFF_SM + SM_SIZE)     // 28024

// per-wave region (float offsets within region)
#define PW_W    0                 // w_s [VSTR]
#define PW_O    VSTR              // o_s [64]
#define PW_H1   (VSTR+64)         // h1_s [64]
#define PW_R    (VSTR+128)        // r_s [96]
#define PW_ATT  (VSTR+224)        // att2u: 4*VSTR ushorts (2*VSTR floats)
#define PW_SIZE (VSTR+224+2*VSTR) // 668
#define LDS_FLOATS (SHARED_FLOATS + 16*PW_SIZE)   // 38712 floats = 154,848 B

// ---- ws layout (float offsets) : only k_pre outputs ----
#define WSV 0                    // vposT [64][VSTR] = 9472
#define WSB (64*VSTR)            // betaT [4][VSTR] = 592
#define WSC (WSB + 4*VSTR)       // vcls 64, uv 64, alga 8  (136)
#define WS_TOTAL (WSC + 136)     // 10200 floats = 40.8 KB

// wave-local barrier: all post-staging LDS deps are intra-wave.
#define WAVE_SYNC() asm volatile("s_waitcnt lgkmcnt(0)" ::: "memory")

__device__ __forceinline__ unsigned short f2b(float f) {
    unsigned u = __float_as_uint(f);
    return (unsigned short)((u + 0x7fffu + ((u >> 16) & 1u)) >> 16);
}

// K1: blocks 0..144 -> vposT col j (transposed!), betaT[.][j]; block 145 -> vcls, uv, alpha/gamma, zero pad cols
__global__ __launch_bounds__(64) void k_pre(const float* __restrict__ pe,
                                            const float* __restrict__ ct,
                                            const float* __restrict__ W,   // in_proj_w (192,64)
                                            const float* __restrict__ bq,  // in_proj_b (192)
                                            float* __restrict__ ws)
{
    const int j = blockIdx.x;
    const int o = threadIdx.x;   // 0..63
    const float4* wq4 = (const float4*)(W + o*64);
    const float4* wk4 = (const float4*)(W + (64 + o)*64);
    const float4* wv4 = (const float4*)(W + (128 + o)*64);
    const float4* ct4 = (const float4*)ct;

    if (j < 145) {
        const float4* p4 = (const float4*)(pe + j*64);
        float sk = bq[64 + o], sv = bq[128 + o], sq = bq[o];
        #pragma unroll
        for (int e = 0; e < 16; ++e) {
            float4 k4 = wk4[e], v4 = wv4[e], q4 = wq4[e], pp = p4[e], cc = ct4[e];
            sk += k4.x*pp.x + k4.y*pp.y + k4.z*pp.z + k4.w*pp.w;
            sv += v4.x*pp.x + v4.y*pp.y + v4.z*pp.z + v4.w*pp.w;
            sq += q4.x*cc.x + q4.y*cc.y + q4.z*cc.z + q4.w*cc.w;
        }
        ws[WSV + o*VSTR + j] = sv;                 // transposed store
        float r = sq * sk;
        #pragma unroll
        for (int off = 1; off < 16; off <<= 1) r += __shfl_xor(r, off);
        if ((o & 15) == 0) ws[WSB + (o >> 4)*VSTR + j] = r;
    } else {
        float sq = bq[o], sk = bq[64 + o], sv = bq[128 + o], suk = 0.f, suv = 0.f;
        #pragma unroll
        for (int e = 0; e < 16; ++e) {
            float4 k4 = wk4[e], v4 = wv4[e], q4 = wq4[e], cc = ct4[e];
            sq += q4.x*cc.x + q4.y*cc.y + q4.z*cc.z + q4.w*cc.w;
            sk += k4.x*cc.x + k4.y*cc.y + k4.z*cc.z + k4.w*cc.w;
            sv += v4.x*cc.x + v4.y*cc.y + v4.z*cc.z + v4.w*cc.w;
            suk += k4.x + k4.y + k4.z + k4.w;
            suv += v4.x + v4.y + v4.z + v4.w;
        }
        ws[WSC + o]      = sv;    // vcls
        ws[WSC + 64 + o] = suv;   // uv
        // zero pad cols 145..147 of vposT (row o)
        ws[WSV + o*VSTR + 145] = 0.f;
        ws[WSV + o*VSTR + 146] = 0.f;
        ws[WSV + o*VSTR + 147] = 0.f;
        float a = sq * suk, g = sq * sk;
        #pragma unroll
        for (int off = 1; off < 16; off <<= 1) {
            a += __shfl_xor(a, off);
            g += __shfl_xor(g, off);
        }
        if ((o & 15) == 0) { ws[WSC + 128 + (o >> 4)] = a; ws[WSC + 128 + 4 + (o >> 4)] = g; }
    }
}

template<int L>
__device__ __forceinline__ void seq_compute(
    const float* __restrict__ xb, int start, int kno, int k, int lane,
    const float* __restrict__ lds, float* __restrict__ pw,
    float* __restrict__ po)
{
    constexpr int N  = L + 1;            // tokens (incl. bias token)
    constexpr int S  = N + 1;            // + cls
    constexpr int NS = (S + 15) / 16;    // score slots per lane
    constexpr int N4 = (N + 3) / 4;      // float4 chunks of attention row

    const float* sm = lds + OFF_SM;
    float* w_s = pw + PW_W;
    unsigned short* au = (unsigned short*)(pw + PW_ATT);

    // ---- load scalar params (one float4 per lane) ----
    if (lane * 4 < L) {
        float4 v = *(const float4*)(xb + start + (size_t)k * L + lane*4);
        *(float4*)(w_s + lane*4) = v;
    }
    if (lane == 0) w_s[L] = xb[start + (size_t)kno * L + k];
    WAVE_SYNC();

    // ---- head-parallel scores + softmax in registers ----
    const int e = lane & 15;
    const int h = lane >> 4;
    const float alpha = sm[SM_ALGA + h];
    const float gam   = sm[SM_ALGA + 4 + h];
    const float* bh   = lds + OFF_BETA + h*VSTR;

    float p[NS];
    float m = -1e30f;
    #pragma unroll
    for (int t = 0; t < NS; ++t) {
        const int s = e + 16*t;
        float v = -1e30f;
        if (s < S) {
            v = (s == 0) ? gam : fmaf(alpha, w_s[s-1], bh[s-1]);
            v *= 0.25f;
        }
        p[t] = v;
        m = fmaxf(m, v);
    }
    #pragma unroll
    for (int off = 1; off < 16; off <<= 1) m = fmaxf(m, __shfl_xor(m, off));

    float sum = 0.f;
    #pragma unroll
    for (int t = 0; t < NS; ++t) {
        const int s = e + 16*t;
        if (s < S) { float ex = __expf(p[t] - m); p[t] = ex; sum += ex; }
    }
    #pragma unroll
    for (int off = 1; off < 16; off <<= 1) sum += __shfl_xor(sum, off);
    const float inv = 1.f / sum;

    // write normalized weights (bf16) + accumulate wsum
    float wsl = 0.f;
    #pragma unroll
    for (int t = 0; t < NS; ++t) {
        const int s = e + 16*t;
        if (s > 0 && s < S) {
            float a = p[t] * inv;
            au[h*VSTR + (s-1)] = f2b(a);
            wsl += a * w_s[s-1];
        }
    }
    #pragma unroll
    for (int off = 1; off < 16; off <<= 1) wsl += __shfl_xor(wsl, off);
    const float wsum = wsl;                               // same in all 16 lanes of group h
    const float a0 = __shfl(p[0] * inv, lane & 48);       // CLS weight from lane h*16
    { int jj = N + e; if (jj < 4*N4) au[h*VSTR + jj] = 0; }
    WAVE_SYNC();

    // ---- o[d] = wsum*uv + a0*vcls + sum_j a[j]*vposT[d][j]  (all LDS) ----
    const int d = lane;
    {
        const float4* vrow = (const float4*)(lds + OFF_VPOST + d*VSTR);
        const unsigned short* ah = au + h*VSTR;
        float c0 = 0.f, c1 = 0.f, c2 = 0.f, c3 = 0.f;
        #pragma unroll
        for (int t = 0; t < N4; ++t) {
            uint2 aa = *(const uint2*)(ah + 4*t);
            float4 v = vrow[t];
            c0 += __uint_as_float(aa.x << 16)          * v.x;
            c1 += __uint_as_float(aa.x & 0xffff0000u)  * v.y;
            c2 += __uint_as_float(aa.y << 16)          * v.z;
            c3 += __uint_as_float(aa.y & 0xffff0000u)  * v.w;
        }
        pw[PW_O + d] = (c0 + c1) + (c2 + c3) + wsum*sm[SM_UV + d] + a0*sm[SM_VCLS + d];
    }
    WAVE_SYNC();

    // ---- out proj + residual(cls) + LN1 ----
    float op = sm[SM_BO + d];
    {
        const float4* wr = (const float4*)(lds + OFF_WO + d*WSTR);
        const float4* os = (const float4*)(pw + PW_O);
        float ax=0, ay=0, az=0, aw=0;
        #pragma unroll
        for (int t = 0; t < 16; ++t) {
            float4 w4 = wr[t], o4 = os[t];
            ax += w4.x*o4.x; ay += w4.y*o4.y; az += w4.z*o4.z; aw += w4.w*o4.w;
        }
        op += (ax + ay) + (az + aw);
    }
    float pre = sm[SM_CT + d] + op;
    float mu = pre;
    #pragma unroll
    for (int off = 32; off; off >>= 1) mu += __shfl_xor(mu, off);
    mu *= (1.f/64.f);
    float dv = pre - mu;
    float var = dv*dv;
    #pragma unroll
    for (int off = 32; off; off >>= 1) var += __shfl_xor(var, off);
    var *= (1.f/64.f);
    float h1 = dv * rsqrtf(var + EPSF) * sm[SM_LN1W + d] + sm[SM_LN1B + d];
    pw[PW_H1 + d] = h1;
    WAVE_SYNC();

    // ---- FF1 (96 outputs) + relu ----
    {
        const float4* hv = (const float4*)(pw + PW_H1);
        {
            const float4* r1 = (const float4*)(lds + OFF_L1 + lane*WSTR);
            float ax=0, ay=0, az=0, aw=0;
            #pragma unroll
            for (int t = 0; t < 16; ++t) {
                float4 w4 = r1[t], h4 = hv[t];
                ax += w4.x*h4.x; ay += w4.y*h4.y; az += w4.z*h4.z; aw += w4.w*h4.w;
            }
            pw[PW_R + lane] = fmaxf(sm[SM_B1 + lane] + (ax+ay) + (az+aw), 0.f);
        }
        if (lane < 32) {
            const float4* r1 = (const float4*)(lds + OFF_L1 + (64 + lane)*WSTR);
            float ax=0, ay=0, az=0, aw=0;
            #pragma unroll
            for (int t = 0; t < 16; ++t) {
                float4 w4 = r1[t], h4 = hv[t];
                ax += w4.x*h4.x; ay += w4.y*h4.y; az += w4.z*h4.z; aw += w4.w*h4.w;
            }
            pw[PW_R + 64 + lane] = fmaxf(sm[SM_B1 + 64 + lane] + (ax+ay) + (az+aw), 0.f);
        }
    }
    WAVE_SYNC();

    // ---- FF2 + residual + LN2 ----
    float f2 = sm[SM_B2 + d];
    {
        const float4* r2 = (const float4*)(lds + OFF_L2 + d*L2STR);
        const float4* rv = (const float4*)(pw + PW_R);
        float ax=0, ay=0, az=0, aw=0;
        #pragma unroll
        for (int t = 0; t < 24; ++t) {
            float4 w4 = r2[t], h4 = rv[t];
            ax += w4.x*h4.x; ay += w4.y*h4.y; az += w4.z*h4.z; aw += w4.w*h4.w;
        }
        f2 += (ax + ay) + (az + aw);
    }
    float pre2 = h1 + f2;
    float mu2 = pre2;
    #pragma unroll
    for (int off = 32; off; off >>= 1) mu2 += __shfl_xor(mu2, off);
    mu2 *= (1.f/64.f);
    float dv2 = pre2 - mu2;
    float var2 = dv2*dv2;
    #pragma unroll
    for (int off = 32; off; off >>= 1) var2 += __shfl_xor(var2, off);
    var2 *= (1.f/64.f);
    float y = dv2 * rsqrtf(var2 + EPSF) * sm[SM_LN2W + d] + sm[SM_LN2B + d];

    po[d]      = y;
    po[64 + d] = y;   // tile (1,1,2)
}

// K2: 256 blocks (1/CU), 1024 threads = 16 waves, one sequence per wave.
__global__ __launch_bounds__(1024, 4) void k_main(
    const float* __restrict__ x,
    const float* __restrict__ ct,
    const float* __restrict__ Wo,  const float* __restrict__ bo,
    const float* __restrict__ L1w, const float* __restrict__ b1,
    const float* __restrict__ L2w, const float* __restrict__ b2,
    const float* __restrict__ ln1w, const float* __restrict__ ln1b,
    const float* __restrict__ ln2w, const float* __restrict__ ln2b,
    const float* __restrict__ ws,
    float* __restrict__ out)
{
    __shared__ float lds[LDS_FLOATS];
    const int tid = threadIdx.x;

    // ---- stage shared data into LDS ----
    {
        // vposT (transposed+padded already in ws): 9472 floats = 2368 float4
        const float4* s4 = (const float4*)(ws + WSV);
        float4* d4 = (float4*)(lds + OFF_VPOST);
        for (int i = tid; i < 2368; i += 1024) d4[i] = s4[i];
        // betaT: 592 floats = 148 float4
        if (tid < 148) ((float4*)(lds + OFF_BETA))[tid] = ((const float4*)(ws + WSB))[tid];
        // Wo 4096 -> stride 68
        for (int idx = tid; idx < 4096; idx += 1024)
            lds[OFF_WO + (idx >> 6)*WSTR + (idx & 63)] = Wo[idx];
        // L1w 6144 -> stride 68
        for (int idx = tid; idx < 6144; idx += 1024)
            lds[OFF_L1 + (idx >> 6)*WSTR + (idx & 63)] = L1w[idx];
        // L2w 6144 -> stride 100
        for (int idx = tid; idx < 6144; idx += 1024) {
            int r = idx / 96, c = idx - r*96;
            lds[OFF_L2 + r*L2STR + c] = L2w[idx];
        }
        // smalls
        if (tid < 64) {
            lds[OFF_SM + SM_CT   + tid] = ct[tid];
            lds[OFF_SM + SM_BO   + tid] = bo[tid];
            lds[OFF_SM + SM_B2   + tid] = b2[tid];
            lds[OFF_SM + SM_LN1W + tid] = ln1w[tid];
            lds[OFF_SM + SM_LN1B + tid] = ln1b[tid];
            lds[OFF_SM + SM_LN2W + tid] = ln2w[tid];
            lds[OFF_SM + SM_LN2B + tid] = ln2b[tid];
        } else if (tid < 256) {
            int t = tid - 64;
            if (t < 96) lds[OFF_SM + SM_B1 + t] = b1[t];
        } else if (tid < 392) {
            int t = tid - 256;              // vcls 64, uv 64, alga 8 contiguous
            lds[OFF_SM + SM_VCLS + t] = ws[WSC + t];
        }
    }
    __syncthreads();

    const int wave = tid >> 6;
    const int lane = tid & 63;
    float* pw = lds + SHARED_FLOATS + wave * PW_SIZE;
    int g = wave * 256 + blockIdx.x;

    if (wave < 4) {
        int b = g >> 8, k = g & 255;
        seq_compute<72>(x + (size_t)b*NPAR, 0, 256, k, lane, lds, pw,
                        out + ((size_t)b*1024 + k)*128);
    } else if (wave < 8) {
        g -= 1024; int b = g >> 8, k = g & 255;
        seq_compute<144>(x + (size_t)b*NPAR, 18688, 256, k, lane, lds, pw,
                         out + ((size_t)b*1024 + 256 + k)*128);
    } else {
        g -= 2048; int b = g >> 9, k = g & 511;
        seq_compute<144>(x + (size_t)b*NPAR, 55808, 512, k, lane, lds, pw,
                         out + ((size_t)b*1024 + 512 + k)*128);
    }
}

extern "C" void kernel_launch(void* const* d_in, const int* in_sizes, int n_in,
                              void* d_out, int out_size, void* d_ws, size_t ws_size,
                              hipStream_t stream) {
    const float* x    = (const float*)d_in[0];
    const float* pe   = (const float*)d_in[1];
    const float* ct   = (const float*)d_in[2];
    const float* Wq   = (const float*)d_in[3];
    const float* bq   = (const float*)d_in[4];
    const float* Wo   = (const float*)d_in[5];
    const float* bo   = (const float*)d_in[6];
    const float* L1w  = (const float*)d_in[7];
    const float* b1   = (const float*)d_in[8];
    const float* L2w  = (const float*)d_in[9];
    const float* b2   = (const float*)d_in[10];
    const float* ln1w = (const float*)d_in[11];
    const float* ln1b = (const float*)d_in[12];
    const float* ln2w = (const float*)d_in[13];
    const float* ln2b = (const float*)d_in[14];
    float* out = (float*)d_out;
    float* ws  = (float*)d_ws;

    k_pre <<<146, 64, 0, stream>>>(pe, ct, Wq, bq, ws);
    k_main<<<256, 1024, 0, stream>>>(x, ct, Wo, bo, L1w, b1, L2w, b2,
                                     ln1w, ln1b, ln2w, ln2b, ws, out);
}

// Round 6
// 20.114 us; speedup vs baseline: 2.5005x; 1.1509x over previous
//
#include <hip/hip_runtime.h>
#include <math.h>

#define NPAR 130048
#define EPSF 1e-5f

typedef _Float16 hfp;
typedef _Float16 h2 __attribute__((ext_vector_type(2)));

#if defined(__has_builtin)
#if __has_builtin(__builtin_amdgcn_fdot2)
#define FDOT2(a,b,c) __builtin_amdgcn_fdot2((a),(b),(c),false)
#endif
#endif
#ifndef FDOT2
#define FDOT2(a,b,c) ((float)(a).x*(float)(b).x + (float)(a).y*(float)(b).y + (c))
#endif

__device__ __forceinline__ h2 f2h2(float f) { union { float f; h2 h; } u; u.f = f; return u.h; }

// ---- f16 row strides (halves): byte stride %16==0 (b128 align) and dword stride %8==4 (bank tiling) ----
#define VSTRH  152           // vposT row (152 h = 304 B = 76 dw)
#define WSTRH  72            // Wo / L1w row (144 B = 36 dw)
#define L2STRH 104           // L2w row (208 B = 52 dw)

// ---- LDS layout (float offsets) ----
#define OFF_VPOST 0                       // f16 [64][VSTRH]        = 4864 floats
#define OFF_WO    4864                    // f16 [64][WSTRH]        = 2304
#define OFF_L1    7168                    // f16 [96][WSTRH]        = 3456
#define OFF_L2    10624                   // f16 [64][L2STRH]       = 3328
#define OFF_BETA  13952                   // f32 [4][152]           = 608
#define OFF_SM    14560                   // f32 smalls             = 680
#define SM_CT   0
#define SM_BO   64
#define SM_B1   128
#define SM_B2   224
#define SM_LN1W 288
#define SM_LN1B 352
#define SM_LN2W 416
#define SM_LN2B 480
#define SM_VCLS 544
#define SM_UV   608
#define SM_ALGA 672
#define SHARED_FLOATS 15240

// per-wave region (float offsets within region); all sub-offsets 16B-aligned
#define PW_W    0                 // f32 w_s [152]
#define PW_O    152               // f16 o   [64]  (32 floats)
#define PW_H1   184               // f16 h1  [64]  (32 floats)
#define PW_R    216               // f16 r   [96]  (48 floats)
#define PW_ATT  264               // f16 att [4][VSTRH] (304 floats)
#define PW_SIZE 568
#define LDS_FLOATS (SHARED_FLOATS + 16*PW_SIZE)   // 24328 floats = 97,312 B

// ---- ws layout (float offsets) ----
#define WSV_F 0        // f16 vposT [64][VSTRH] packed = 4864 floats
#define WSB_F 4864     // f32 betaT [4][152]
#define WSC_F 5472     // vcls 64, uv 64, alga 8 (136 floats)

// wave-local barrier: all post-staging LDS deps are intra-wave.
#define WAVE_SYNC() asm volatile("s_waitcnt lgkmcnt(0)" ::: "memory")

// K1: blocks 0..144 -> vposT col j (f16, transposed), betaT[.][j]; block 145 -> vcls/uv/alga + pads
__global__ __launch_bounds__(64) void k_pre(const float* __restrict__ pe,
                                            const float* __restrict__ ct,
                                            const float* __restrict__ W,   // in_proj_w (192,64)
                                            const float* __restrict__ bq,  // in_proj_b (192)
                                            float* __restrict__ ws)
{
    const int j = blockIdx.x;
    const int o = threadIdx.x;   // 0..63
    const float4* wq4 = (const float4*)(W + o*64);
    const float4* wk4 = (const float4*)(W + (64 + o)*64);
    const float4* wv4 = (const float4*)(W + (128 + o)*64);
    const float4* ct4 = (const float4*)ct;
    hfp* wsh = (hfp*)ws;

    if (j < 145) {
        const float4* p4 = (const float4*)(pe + j*64);
        float sk = bq[64 + o], sv = bq[128 + o], sq = bq[o];
        #pragma unroll
        for (int e = 0; e < 16; ++e) {
            float4 k4 = wk4[e], v4 = wv4[e], q4 = wq4[e], pp = p4[e], cc = ct4[e];
            sk += k4.x*pp.x + k4.y*pp.y + k4.z*pp.z + k4.w*pp.w;
            sv += v4.x*pp.x + v4.y*pp.y + v4.z*pp.z + v4.w*pp.w;
            sq += q4.x*cc.x + q4.y*cc.y + q4.z*cc.z + q4.w*cc.w;
        }
        wsh[o*VSTRH + j] = (hfp)sv;                // transposed f16 store
        float r = sq * sk;
        #pragma unroll
        for (int off = 1; off < 16; off <<= 1) r += __shfl_xor(r, off);
        if ((o & 15) == 0) ws[WSB_F + (o >> 4)*152 + j] = r;
    } else {
        float sq = bq[o], sk = bq[64 + o], sv = bq[128 + o], suk = 0.f, suv = 0.f;
        #pragma unroll
        for (int e = 0; e < 16; ++e) {
            float4 k4 = wk4[e], v4 = wv4[e], q4 = wq4[e], cc = ct4[e];
            sq += q4.x*cc.x + q4.y*cc.y + q4.z*cc.z + q4.w*cc.w;
            sk += k4.x*cc.x + k4.y*cc.y + k4.z*cc.z + k4.w*cc.w;
            sv += v4.x*cc.x + v4.y*cc.y + v4.z*cc.z + v4.w*cc.w;
            suk += k4.x + k4.y + k4.z + k4.w;
            suv += v4.x + v4.y + v4.z + v4.w;
        }
        ws[WSC_F + o]      = sv;    // vcls
        ws[WSC_F + 64 + o] = suv;   // uv
        #pragma unroll
        for (int jj = 145; jj < VSTRH; ++jj) wsh[o*VSTRH + jj] = (hfp)0.f;
        float a = sq * suk, g = sq * sk;
        #pragma unroll
        for (int off = 1; off < 16; off <<= 1) {
            a += __shfl_xor(a, off);
            g += __shfl_xor(g, off);
        }
        if ((o & 15) == 0) { ws[WSC_F + 128 + (o >> 4)] = a; ws[WSC_F + 128 + 4 + (o >> 4)] = g; }
    }
}

template<int L>
__device__ __forceinline__ void seq_compute(
    float4 wv, float wb, int lane,
    float* __restrict__ lds, float* __restrict__ pw,
    float* __restrict__ po)
{
    constexpr int N  = L + 1;              // tokens (incl. bias token)
    constexpr int S  = N + 1;              // + cls
    constexpr int NS = (S + 15) / 16;      // score slots per lane
    constexpr int N8 = ((N + 7) / 8) * 8;  // f16 row padded to 8
    constexpr int NT = N8 / 8;             // b128 chunks (8 halves each)

    const float* sm = lds + OFF_SM;
    const hfp* ldsh = (const hfp*)lds;
    float* w_s = pw + PW_W;
    hfp* oh  = (hfp*)(pw + PW_O);
    hfp* h1h = (hfp*)(pw + PW_H1);
    hfp* rh  = (hfp*)(pw + PW_R);
    hfp* att = (hfp*)(pw + PW_ATT);

    // ---- write preloaded scalar params ----
    if (lane * 4 < L) *(float4*)(w_s + lane*4) = wv;
    if (lane == 0) w_s[L] = wb;
    WAVE_SYNC();

    // ---- head-parallel scores + softmax in registers ----
    const int e = lane & 15;
    const int h = lane >> 4;
    const float alpha = sm[SM_ALGA + h];
    const float gam   = sm[SM_ALGA + 4 + h];
    const float* bh   = lds + OFF_BETA + h*152;

    float p[NS];
    float m = -1e30f;
    #pragma unroll
    for (int t = 0; t < NS; ++t) {
        const int s = e + 16*t;
        float v = -1e30f;
        if (s < S) {
            v = (s == 0) ? gam : fmaf(alpha, w_s[s-1], bh[s-1]);
            v *= 0.25f;
        }
        p[t] = v;
        m = fmaxf(m, v);
    }
    #pragma unroll
    for (int off = 1; off < 16; off <<= 1) m = fmaxf(m, __shfl_xor(m, off));

    float sum = 0.f;
    #pragma unroll
    for (int t = 0; t < NS; ++t) {
        const int s = e + 16*t;
        if (s < S) { float ex = __expf(p[t] - m); p[t] = ex; sum += ex; }
    }
    #pragma unroll
    for (int off = 1; off < 16; off <<= 1) sum += __shfl_xor(sum, off);
    const float inv = 1.f / sum;

    // write normalized weights (f16) + accumulate wsum
    float wsl = 0.f;
    #pragma unroll
    for (int t = 0; t < NS; ++t) {
        const int s = e + 16*t;
        if (s > 0 && s < S) {
            float a = p[t] * inv;
            att[h*VSTRH + (s-1)] = (hfp)a;
            wsl += a * w_s[s-1];
        }
    }
    #pragma unroll
    for (int off = 1; off < 16; off <<= 1) wsl += __shfl_xor(wsl, off);
    const float wsum = wsl;
    const float a0 = __shfl(p[0] * inv, lane & 48);   // CLS weight from lane h*16
    { int jj = N + e; if (jj < N8) att[h*VSTRH + jj] = (hfp)0.f; }
    WAVE_SYNC();

    // ---- o[d] = wsum*uv + a0*vcls + sum_j a[j]*vposT[d][j]  (f16 dot2) ----
    const int d = lane;
    {
        const float4* vrow = (const float4*)(ldsh + d*VSTRH);          // OFF_VPOST==0
        const float4* arow = (const float4*)(att + h*VSTRH);
        float c0 = 0.f, c1 = 0.f, c2 = 0.f, c3 = 0.f;
        #pragma unroll
        for (int t = 0; t < NT; ++t) {
            float4 av = arow[t], vvv = vrow[t];
            c0 = FDOT2(f2h2(av.x), f2h2(vvv.x), c0);
            c1 = FDOT2(f2h2(av.y), f2h2(vvv.y), c1);
            c2 = FDOT2(f2h2(av.z), f2h2(vvv.z), c2);
            c3 = FDOT2(f2h2(av.w), f2h2(vvv.w), c3);
        }
        float ov = (c0 + c1) + (c2 + c3) + wsum*sm[SM_UV + d] + a0*sm[SM_VCLS + d];
        oh[d] = (hfp)ov;
    }
    WAVE_SYNC();

    // ---- out proj + residual(cls) + LN1 ----
    float op = sm[SM_BO + d];
    {
        const float4* wr = (const float4*)(ldsh + OFF_WO*2 + d*WSTRH);
        const float4* ov = (const float4*)oh;
        float c0 = 0.f, c1 = 0.f, c2 = 0.f, c3 = 0.f;
        #pragma unroll
        for (int t = 0; t < 8; ++t) {
            float4 w4 = wr[t], o4 = ov[t];
            c0 = FDOT2(f2h2(w4.x), f2h2(o4.x), c0);
            c1 = FDOT2(f2h2(w4.y), f2h2(o4.y), c1);
            c2 = FDOT2(f2h2(w4.z), f2h2(o4.z), c2);
            c3 = FDOT2(f2h2(w4.w), f2h2(o4.w), c3);
        }
        op += (c0 + c1) + (c2 + c3);
    }
    float pre = sm[SM_CT + d] + op;
    float mu = pre;
    #pragma unroll
    for (int off = 32; off; off >>= 1) mu += __shfl_xor(mu, off);
    mu *= (1.f/64.f);
    float dv = pre - mu;
    float var = dv*dv;
    #pragma unroll
    for (int off = 32; off; off >>= 1) var += __shfl_xor(var, off);
    var *= (1.f/64.f);
    float h1 = dv * rsqrtf(var + EPSF) * sm[SM_LN1W + d] + sm[SM_LN1B + d];
    h1h[d] = (hfp)h1;
    WAVE_SYNC();

    // ---- FF1 (96 outputs) + relu ----
    {
        const float4* hv = (const float4*)h1h;
        {
            const float4* r1 = (const float4*)(ldsh + OFF_L1*2 + lane*WSTRH);
            float c0 = 0.f, c1 = 0.f, c2 = 0.f, c3 = 0.f;
            #pragma unroll
            for (int t = 0; t < 8; ++t) {
                float4 w4 = r1[t], h4 = hv[t];
                c0 = FDOT2(f2h2(w4.x), f2h2(h4.x), c0);
                c1 = FDOT2(f2h2(w4.y), f2h2(h4.y), c1);
                c2 = FDOT2(f2h2(w4.z), f2h2(h4.z), c2);
                c3 = FDOT2(f2h2(w4.w), f2h2(h4.w), c3);
            }
            rh[lane] = (hfp)fmaxf(sm[SM_B1 + lane] + (c0+c1) + (c2+c3), 0.f);
        }
        if (lane < 32) {
            const float4* r1 = (const float4*)(ldsh + OFF_L1*2 + (64 + lane)*WSTRH);
            float c0 = 0.f, c1 = 0.f, c2 = 0.f, c3 = 0.f;
            #pragma unroll
            for (int t = 0; t < 8; ++t) {
                float4 w4 = r1[t], h4 = hv[t];
                c0 = FDOT2(f2h2(w4.x), f2h2(h4.x), c0);
                c1 = FDOT2(f2h2(w4.y), f2h2(h4.y), c1);
                c2 = FDOT2(f2h2(w4.z), f2h2(h4.z), c2);
                c3 = FDOT2(f2h2(w4.w), f2h2(h4.w), c3);
            }
            rh[64 + lane] = (hfp)fmaxf(sm[SM_B1 + 64 + lane] + (c0+c1) + (c2+c3), 0.f);
        }
    }
    WAVE_SYNC();

    // ---- FF2 + residual + LN2 ----
    float f2 = sm[SM_B2 + d];
    {
        const float4* r2 = (const float4*)(ldsh + OFF_L2*2 + d*L2STRH);
        const float4* rv = (const float4*)rh;
        float c0 = 0.f, c1 = 0.f, c2 = 0.f, c3 = 0.f;
        #pragma unroll
        for (int t = 0; t < 12; ++t) {
            float4 w4 = r2[t], h4 = rv[t];
            c0 = FDOT2(f2h2(w4.x), f2h2(h4.x), c0);
            c1 = FDOT2(f2h2(w4.y), f2h2(h4.y), c1);
            c2 = FDOT2(f2h2(w4.z), f2h2(h4.z), c2);
            c3 = FDOT2(f2h2(w4.w), f2h2(h4.w), c3);
        }
        f2 += (c0 + c1) + (c2 + c3);
    }
    float pre2 = h1 + f2;
    float mu2 = pre2;
    #pragma unroll
    for (int off = 32; off; off >>= 1) mu2 += __shfl_xor(mu2, off);
    mu2 *= (1.f/64.f);
    float dv2 = pre2 - mu2;
    float var2 = dv2*dv2;
    #pragma unroll
    for (int off = 32; off; off >>= 1) var2 += __shfl_xor(var2, off);
    var2 *= (1.f/64.f);
    float y = dv2 * rsqrtf(var2 + EPSF) * sm[SM_LN2W + d] + sm[SM_LN2B + d];

    po[d]      = y;
    po[64 + d] = y;   // tile (1,1,2)
}

// K2: 256 blocks, 1024 threads = 16 waves, one sequence per wave.
__global__ __launch_bounds__(1024, 4) void k_main(
    const float* __restrict__ x,
    const float* __restrict__ ct,
    const float* __restrict__ Wo,  const float* __restrict__ bo,
    const float* __restrict__ L1w, const float* __restrict__ b1,
    const float* __restrict__ L2w, const float* __restrict__ b2,
    const float* __restrict__ ln1w, const float* __restrict__ ln1b,
    const float* __restrict__ ln2w, const float* __restrict__ ln2b,
    const float* __restrict__ ws,
    float* __restrict__ out)
{
    __shared__ float lds[LDS_FLOATS];
    const int tid  = threadIdx.x;
    const int wave = tid >> 6;
    const int lane = tid & 63;

    // ---- per-wave sequence identity + early global load (hides under staging) ----
    int g = wave * 256 + blockIdx.x;
    int start, L, kno, k, outidx, b;
    if (wave < 4)       { b = g >> 8; k = g & 255;            start = 0;     L = 72;  kno = 256; outidx = b*1024 + k; }
    else if (wave < 8)  { g -= 1024; b = g >> 8; k = g & 255; start = 18688; L = 144; kno = 256; outidx = b*1024 + 256 + k; }
    else                { g -= 2048; b = g >> 9; k = g & 511; start = 55808; L = 144; kno = 512; outidx = b*1024 + 512 + k; }
    const float* xb = x + (size_t)b * NPAR;
    float4 wv = make_float4(0.f, 0.f, 0.f, 0.f);
    if (lane * 4 < L) wv = *(const float4*)(xb + start + (size_t)k * L + lane*4);
    float wb = (lane == 0) ? xb[start + (size_t)kno * L + k] : 0.f;

    // ---- stage shared data into LDS ----
    {
        hfp* ldsh = (hfp*)lds;
        // vposT (f16, already packed in ws): 4864 floats = 1216 float4
        const float4* s4 = (const float4*)(ws + WSV_F);
        float4* d4 = (float4*)(lds + OFF_VPOST);
        for (int i = tid; i < 1216; i += 1024) d4[i] = s4[i];
        // betaT: 608 floats = 152 float4
        if (tid < 152) ((float4*)(lds + OFF_BETA))[tid] = ((const float4*)(ws + WSB_F))[tid];
        // Wo 4096 f32 -> f16 stride 72
        for (int idx = tid; idx < 4096; idx += 1024)
            ldsh[OFF_WO*2 + (idx >> 6)*WSTRH + (idx & 63)] = (hfp)Wo[idx];
        // L1w 6144 -> f16 stride 72
        for (int idx = tid; idx < 6144; idx += 1024)
            ldsh[OFF_L1*2 + (idx >> 6)*WSTRH + (idx & 63)] = (hfp)L1w[idx];
        // L2w 6144 -> f16 stride 104
        for (int idx = tid; idx < 6144; idx += 1024) {
            int r = idx / 96, c = idx - r*96;
            ldsh[OFF_L2*2 + r*L2STRH + c] = (hfp)L2w[idx];
        }
        // smalls
        if (tid < 64) {
            lds[OFF_SM + SM_CT   + tid] = ct[tid];
            lds[OFF_SM + SM_BO   + tid] = bo[tid];
            lds[OFF_SM + SM_B2   + tid] = b2[tid];
            lds[OFF_SM + SM_LN1W + tid] = ln1w[tid];
            lds[OFF_SM + SM_LN1B + tid] = ln1b[tid];
            lds[OFF_SM + SM_LN2W + tid] = ln2w[tid];
            lds[OFF_SM + SM_LN2B + tid] = ln2b[tid];
        } else if (tid < 256) {
            int t = tid - 64;
            if (t < 96) lds[OFF_SM + SM_B1 + t] = b1[t];
        } else if (tid < 392) {
            int t = tid - 256;              // vcls 64, uv 64, alga 8 contiguous
            lds[OFF_SM + SM_VCLS + t] = ws[WSC_F + t];
        }
    }
    __syncthreads();

    float* pw = lds + SHARED_FLOATS + wave * PW_SIZE;
    float* po = out + (size_t)outidx * 128;

    if (wave < 4) seq_compute<72>(wv, wb, lane, lds, pw, po);
    else          seq_compute<144>(wv, wb, lane, lds, pw, po);
}

extern "C" void kernel_launch(void* const* d_in, const int* in_sizes, int n_in,
                              void* d_out, int out_size, void* d_ws, size_t ws_size,
                              hipStream_t stream) {
    const float* x    = (const float*)d_in[0];
    const float* pe   = (const float*)d_in[1];
    const float* ct   = (const float*)d_in[2];
    const float* Wq   = (const float*)d_in[3];
    const float* bq   = (const float*)d_in[4];
    const float* Wo   = (const float*)d_in[5];
    const float* bo   = (const float*)d_in[6];
    const float* L1w  = (const float*)d_in[7];
    const float* b1   = (const float*)d_in[8];
    const float* L2w  = (const float*)d_in[9];
    const float* b2   = (const float*)d_in[10];
    const float* ln1w = (const float*)d_in[11];
    const float* ln1b = (const float*)d_in[12];
    const float* ln2w = (const float*)d_in[13];
    const float* ln2b = (const float*)d_in[14];
    float* out = (float*)d_out;
    float* ws  = (float*)d_ws;

    k_pre <<<146, 64, 0, stream>>>(pe, ct, Wq, bq, ws);
    k_main<<<256, 1024, 0, stream>>>(x, ct, Wo, bo, L1w, b1, L2w, b2,
                                     ln1w, ln1b, ln2w, ln2b, ws, out);
}